// Round 13
// baseline (205.509 us; speedup 1.0000x reference)
//
#include <hip/hip_runtime.h>

// GCN encoder: h = relu(agg(x)@W1 + b1); out = agg(h@W2) + b2
// agg = symmetric-normalized adjacency (self loops) aggregation.
// Identities: agg(x@W)==agg(x)@W; (dinv*h)@W==dinv*(h@W); di*(acc@W)==(di*acc)@W.
// Pipeline (5 dispatches):
//   memset counts;
//   count_conv:  INTERLEAVED blocks: even=per-edge atomicAdd rank (atomic
//                floor ~24G ops/s), odd=x->bf16 convert, trailing 12=W prep.
//   fill:        atomic-free slab scatter col[dst*CAP+rank]=src
//   k_layer1:    per 16-node block: gather-agg (8-wide edge unroll, per-edge
//                w=rsqrt(counts[s]+1)) -> LDS -> MFMA @W1 (+bias,relu,*di,*di)
//                -> LDS -> MFMA @W2 -> bf16 layer-2 table
//   agg2:        gather-sum over prescaled table (8-wide), *di + b2 -> f32 out

constexpr int N  = 100000;
constexpr int E  = 1600000;
constexpr int CAP = 56;                    // slab capacity; P(Poisson(16)>56)~1e-11
constexpr int EB = (E + 255) / 256;        // 6250 edge blocks

typedef unsigned short u16;
typedef __attribute__((ext_vector_type(8))) short bf16x8;  // 8 bf16 = 4 VGPR
typedef __attribute__((ext_vector_type(4))) float f32x4;

// ---------------- bf16 helpers ----------------

__device__ __forceinline__ unsigned bf16rne(float f) {
  unsigned u = __float_as_uint(f);
  return (u + 0x7fffu + ((u >> 16) & 1u)) >> 16;
}
__device__ __forceinline__ unsigned pk(float lo, float hi) {
  return bf16rne(lo) | (bf16rne(hi) << 16);
}
__device__ __forceinline__ void acc8(float (&a)[8], const uint4& u, float wgt) {
  a[0] = fmaf(wgt, __uint_as_float(u.x << 16), a[0]);
  a[1] = fmaf(wgt, __uint_as_float(u.x & 0xffff0000u), a[1]);
  a[2] = fmaf(wgt, __uint_as_float(u.y << 16), a[2]);
  a[3] = fmaf(wgt, __uint_as_float(u.y & 0xffff0000u), a[3]);
  a[4] = fmaf(wgt, __uint_as_float(u.z << 16), a[4]);
  a[5] = fmaf(wgt, __uint_as_float(u.z & 0xffff0000u), a[5]);
  a[6] = fmaf(wgt, __uint_as_float(u.w << 16), a[6]);
  a[7] = fmaf(wgt, __uint_as_float(u.w & 0xffff0000u), a[7]);
}

// ------- fused: degree count (+rank) | x -> bf16 | W -> frag tables --------

__global__ __launch_bounds__(256) void k_count_conv(
    const int* __restrict__ dst, int* __restrict__ counts, int* __restrict__ rank,
    const float* __restrict__ x, uint4* __restrict__ xb,
    const float* __restrict__ W1, const float* __restrict__ W2,
    uint4* __restrict__ Wb1, uint4* __restrict__ Wb2) {
  int b = blockIdx.x;
  if (b < 2 * EB) {
    int c = b >> 1;
    if (b & 1) {                             // convert block
      int i = c * 256 + threadIdx.x;         // one uint4 (8 bf16) per thread
      if (i >= N * 16) return;
      const float4* x4 = reinterpret_cast<const float4*>(x);
      float4 v0 = x4[(size_t)i * 2];
      float4 v1 = x4[(size_t)i * 2 + 1];
      uint4 o;
      o.x = pk(v0.x, v0.y);
      o.y = pk(v0.z, v0.w);
      o.z = pk(v1.x, v1.y);
      o.w = pk(v1.z, v1.w);
      xb[i] = o;
    } else {                                 // edge (count) block
      int e = c * 256 + threadIdx.x;
      if (e < E) rank[e] = atomicAdd(&counts[dst[e]], 1);
    }
  } else {                                   // weight prep
    int t = (b - 2 * EB) * 256 + threadIdx.x;
    if (t < 2048) {                          // W1: 8 ct * 4 kc * 64 lanes
      int ct = t >> 8, kc = (t >> 6) & 3, l = t & 63;
      int k0 = kc * 32 + (l >> 4) * 8;
      int c = ct * 16 + (l & 15);
      uint4 o;
      o.x = pk(W1[(k0 + 0) * 128 + c], W1[(k0 + 1) * 128 + c]);
      o.y = pk(W1[(k0 + 2) * 128 + c], W1[(k0 + 3) * 128 + c]);
      o.z = pk(W1[(k0 + 4) * 128 + c], W1[(k0 + 5) * 128 + c]);
      o.w = pk(W1[(k0 + 6) * 128 + c], W1[(k0 + 7) * 128 + c]);
      Wb1[t] = o;
    } else if (t < 3072) {                   // W2: 4 ct * 4 kc * 64 lanes
      int u = t - 2048;
      int ct = u >> 8, kc = (u >> 6) & 3, l = u & 63;
      int k0 = kc * 32 + (l >> 4) * 8;
      int c = ct * 16 + (l & 15);
      uint4 o;
      o.x = pk(W2[(k0 + 0) * 64 + c], W2[(k0 + 1) * 64 + c]);
      o.y = pk(W2[(k0 + 2) * 64 + c], W2[(k0 + 3) * 64 + c]);
      o.z = pk(W2[(k0 + 4) * 64 + c], W2[(k0 + 5) * 64 + c]);
      o.w = pk(W2[(k0 + 6) * 64 + c], W2[(k0 + 7) * 64 + c]);
      Wb2[u] = o;
    }
  }
}

// ---------------- atomic-free slab fill ----------------

__global__ __launch_bounds__(256) void k_fill(
    const int* __restrict__ src, const int* __restrict__ dst,
    const int* __restrict__ rank, int* __restrict__ col) {
  int e = blockIdx.x * 256 + threadIdx.x;
  if (e < E) col[(size_t)dst[e] * CAP + rank[e]] = src[e];
}

// ---------------- MEGA layer 1: agg -> @W1 -> epi -> @W2 -> table ----------
// One block = 16 nodes, 256 threads.
// Phase A: thread (n=tid>>4, d8=tid&15) aggregates 8 dims of node n with an
//   8-wide edge unroll (8 independent col->counts/xb chains in flight).
// Phase B: wave w computes cols [w*32,w*32+32) of acc@W1:
//   v = relu(di[r]*v + b1[c]) * di[r]  -> lds_h (bf16)
// Phase C: wave w computes cols [w*16,w*16+16) of hs@W2 -> xa2 global (bf16).

__global__ __launch_bounds__(256) void k_layer1(
    const uint4* __restrict__ xb, const int* __restrict__ counts,
    const int* __restrict__ col, const float* __restrict__ b1,
    const uint4* __restrict__ Wb1, const uint4* __restrict__ Wb2,
    u16* __restrict__ xa2) {
  __shared__ u16 lds_a[16][136];
  __shared__ u16 lds_h[16][136];
  __shared__ float lds_di[16];
  const int tid = threadIdx.x;
  const int nodeBase = blockIdx.x * 16;

  // ---- phase A: gather-aggregate (8-wide) ----
  {
    const int n = tid >> 4;
    const int d8 = tid & 15;
    const int node = nodeBase + n;
    const int cnt = counts[node];
    const float wself = rsqrtf((float)(cnt + 1));
    if (d8 == 0) lds_di[n] = wself;
    const size_t s0 = (size_t)node * CAP;

    float a[8] = {0, 0, 0, 0, 0, 0, 0, 0};
    acc8(a, xb[(size_t)node * 16 + d8], wself);  // self loop
    int e = 0;
    for (; e + 8 <= cnt; e += 8) {
      int s[8];
      #pragma unroll
      for (int q = 0; q < 8; ++q) s[q] = col[s0 + e + q];
      float wq[8];
      #pragma unroll
      for (int q = 0; q < 8; ++q) wq[q] = rsqrtf((float)(counts[s[q]] + 1));
      uint4 v[8];
      #pragma unroll
      for (int q = 0; q < 8; ++q) v[q] = xb[(size_t)s[q] * 16 + d8];
      #pragma unroll
      for (int q = 0; q < 8; ++q) acc8(a, v[q], wq[q]);
    }
    for (; e + 4 <= cnt; e += 4) {
      int s[4];
      #pragma unroll
      for (int q = 0; q < 4; ++q) s[q] = col[s0 + e + q];
      float wq[4];
      #pragma unroll
      for (int q = 0; q < 4; ++q) wq[q] = rsqrtf((float)(counts[s[q]] + 1));
      uint4 v[4];
      #pragma unroll
      for (int q = 0; q < 4; ++q) v[q] = xb[(size_t)s[q] * 16 + d8];
      #pragma unroll
      for (int q = 0; q < 4; ++q) acc8(a, v[q], wq[q]);
    }
    for (; e < cnt; ++e) {                       // exact tail
      int s = col[s0 + e];
      float w = rsqrtf((float)(counts[s] + 1));
      acc8(a, xb[(size_t)s * 16 + d8], w);
    }
    uint4 o;
    o.x = pk(a[0], a[1]);
    o.y = pk(a[2], a[3]);
    o.z = pk(a[4], a[5]);
    o.w = pk(a[6], a[7]);
    *reinterpret_cast<uint4*>(&lds_a[n][d8 * 8]) = o;
  }
  __syncthreads();

  // ---- phase B: acc@W1, epilogue relu(di*v+b1)*di -> lds_h ----
  const int lane = tid & 63;
  const int w = tid >> 6;
  const int lr = lane & 15;
  const int lk = lane >> 4;
  const bf16x8* Wf1 = reinterpret_cast<const bf16x8*>(Wb1);
  const bf16x8* Wf2 = reinterpret_cast<const bf16x8*>(Wb2);
  const f32x4 fz = {0.f, 0.f, 0.f, 0.f};
  {
    bf16x8 af[4];
    #pragma unroll
    for (int kc = 0; kc < 4; ++kc)
      af[kc] = *reinterpret_cast<const bf16x8*>(&lds_a[lr][kc * 32 + lk * 8]);
    f32x4 acc1[2] = {fz, fz};
    #pragma unroll
    for (int kc = 0; kc < 4; ++kc) {
      #pragma unroll
      for (int i = 0; i < 2; ++i) {
        bf16x8 bf = Wf1[((w * 2 + i) * 4 + kc) * 64 + lane];
        acc1[i] = __builtin_amdgcn_mfma_f32_16x16x32_bf16(af[kc], bf, acc1[i], 0, 0, 0);
      }
    }
    #pragma unroll
    for (int i = 0; i < 2; ++i) {
      const int c = (w * 2 + i) * 16 + lr;
      const float bl = b1[c];
      #pragma unroll
      for (int ri = 0; ri < 4; ++ri) {
        const int r = lk * 4 + ri;
        const float di = lds_di[r];
        float v = fmaxf(di * acc1[i][ri] + bl, 0.f) * di;
        lds_h[r][c] = (u16)bf16rne(v);
      }
    }
  }
  __syncthreads();

  // ---- phase C: hs@W2 -> layer-2 table (bf16) ----
  {
    bf16x8 a2[4];
    #pragma unroll
    for (int kc = 0; kc < 4; ++kc)
      a2[kc] = *reinterpret_cast<const bf16x8*>(&lds_h[lr][kc * 32 + lk * 8]);
    f32x4 acc2 = fz;
    #pragma unroll
    for (int kc = 0; kc < 4; ++kc) {
      bf16x8 bf = Wf2[(w * 4 + kc) * 64 + lane];
      acc2 = __builtin_amdgcn_mfma_f32_16x16x32_bf16(a2[kc], bf, acc2, 0, 0, 0);
    }
    #pragma unroll
    for (int ri = 0; ri < 4; ++ri) {
      const int row = nodeBase + lk * 4 + ri;
      xa2[(size_t)row * 64 + w * 16 + lr] = (u16)bf16rne(acc2[ri]);
    }
  }
}

// ---------------- layer-2 aggregation: prescaled bf16 table ----------------
// out[i] = rsqrt(cnt_i+1) * ( sum_s t[s] + t[i] ) + b2    (f32 out)

__global__ __launch_bounds__(256) void k_agg2(
    const uint4* __restrict__ t, const int* __restrict__ counts,
    const int* __restrict__ col, const float* __restrict__ bias,
    float* __restrict__ out) {
  const int node = blockIdx.x * 32 + (threadIdx.x >> 3);
  const int lane = threadIdx.x & 7;            // 8 lanes x 8 dims = 64
  if (node >= N) return;
  const size_t s0 = (size_t)node * CAP;
  const int cnt = counts[node];
  const float di = rsqrtf((float)(cnt + 1));

  float a[8] = {0, 0, 0, 0, 0, 0, 0, 0};
  acc8(a, t[(size_t)node * 8 + lane], 1.0f);   // self loop (prescaled)
  int e = 0;
  for (; e + 8 <= cnt; e += 8) {
    int s[8];
    #pragma unroll
    for (int q = 0; q < 8; ++q) s[q] = col[s0 + e + q];
    uint4 v[8];
    #pragma unroll
    for (int q = 0; q < 8; ++q) v[q] = t[(size_t)s[q] * 8 + lane];
    #pragma unroll
    for (int q = 0; q < 8; ++q) acc8(a, v[q], 1.0f);
  }
  for (; e + 4 <= cnt; e += 4) {
    int s[4];
    #pragma unroll
    for (int q = 0; q < 4; ++q) s[q] = col[s0 + e + q];
    uint4 v[4];
    #pragma unroll
    for (int q = 0; q < 4; ++q) v[q] = t[(size_t)s[q] * 8 + lane];
    #pragma unroll
    for (int q = 0; q < 4; ++q) acc8(a, v[q], 1.0f);
  }
  for (; e < cnt; ++e)
    acc8(a, t[(size_t)col[s0 + e] * 8 + lane], 1.0f);

  const float4* b4 = reinterpret_cast<const float4*>(bias) + lane * 2;
  float4 b0 = b4[0], b1v = b4[1];
  float4 r0 = {fmaf(di, a[0], b0.x), fmaf(di, a[1], b0.y),
               fmaf(di, a[2], b0.z), fmaf(di, a[3], b0.w)};
  float4 r1 = {fmaf(di, a[4], b1v.x), fmaf(di, a[5], b1v.y),
               fmaf(di, a[6], b1v.z), fmaf(di, a[7], b1v.w)};
  float4* o4 = reinterpret_cast<float4*>(out) + (size_t)node * 16 + lane * 2;
  o4[0] = r0;
  o4[1] = r1;
}

// ---------------- launch ----------------

extern "C" void kernel_launch(void* const* d_in, const int* in_sizes, int n_in,
                              void* d_out, int out_size, void* d_ws, size_t ws_size,
                              hipStream_t stream) {
  const float* x  = (const float*)d_in[0];
  const int*   ei = (const int*)d_in[1];
  const float* W1 = (const float*)d_in[2];
  const float* b1 = (const float*)d_in[3];
  const float* W2 = (const float*)d_in[4];
  const float* b2 = (const float*)d_in[5];
  float* out = (float*)d_out;
  const int* src = ei;
  const int* dst = ei + E;

  char* p = (char*)d_ws;
  auto alloc = [&](size_t bytes) {
    void* q = p;
    p += (bytes + 255) & ~size_t(255);
    return q;
  };
  int*   counts = (int*)alloc((size_t)N * 4);        // 0.4 MB
  int*   rank   = (int*)alloc((size_t)E * 4);        // 6.4 MB
  int*   col    = (int*)alloc((size_t)N * CAP * 4);  // 22.4 MB slab
  uint4* xb     = (uint4*)alloc((size_t)N * 256);    // 25.6 MB bf16 x (unscaled)
  u16*   xa2    = (u16*)alloc((size_t)N * 64 * 2);   // 12.8 MB layer-2 table
  uint4* Wb1    = (uint4*)alloc(2048 * 16);
  uint4* Wb2    = (uint4*)alloc(1024 * 16);

  (void)hipMemsetAsync(counts, 0, (size_t)N * 4, stream);
  k_count_conv<<<2 * EB + 12, 256, 0, stream>>>(dst, counts, rank, x, xb,
                                                W1, W2, Wb1, Wb2);
  k_fill<<<EB, 256, 0, stream>>>(src, dst, rank, col);

  // layer 1 fused: gather-agg -> @W1 (+bias,relu,*di,*di) -> @W2 -> bf16 table
  k_layer1<<<N / 16, 256, 0, stream>>>(xb, counts, col, b1, Wb1, Wb2, xa2);

  // layer 2: gather-agg over prescaled table, *di + b2 -> f32 out
  k_agg2<<<N / 32, 256, 0, stream>>>(
      reinterpret_cast<const uint4*>(xa2), counts, col, b2, out);
}

// Round 14
// 200.304 us; speedup vs baseline: 1.0260x; 1.0260x over previous
//
#include <hip/hip_runtime.h>

// GCN encoder: h = relu(agg(x)@W1 + b1); out = agg(h@W2) + b2
// agg = symmetric-normalized adjacency (self loops) aggregation.
// Identities: agg(x@W)==agg(x)@W; (dinv*h)@W==dinv*(h@W); di*(acc@W)==(di*acc)@W.
// Pipeline (5 dispatches):
//   memset counts;
//   count_conv:  INTERLEAVED blocks: even=per-edge atomicAdd rank (atomic
//                floor ~24G ops/s, BW-idle), odd=x->bf16 convert (BW-bound),
//                trailing 12 = W->bf16 MFMA-frag prep. Convert+wprep hide
//                under the atomic pass instead of tailing it.
//   fill:        atomic-free slab scatter col[dst*CAP+rank]=src (write-
//                allocate floor ~102MB)
//   k_layer1:    per 16-node block: gather-agg (4-wide unroll — 8-wide
//                measured SLOWER: VGPR 36->56 cut occupancy 64->39%) ->
//                LDS -> MFMA @W1 (+bias,relu,*di,*di) -> LDS -> MFMA @W2
//                -> bf16 layer-2 table
//   agg2:        gather-sum over prescaled table, *di + b2 -> f32 out

constexpr int N  = 100000;
constexpr int E  = 1600000;
constexpr int CAP = 56;                    // slab capacity; P(Poisson(16)>56)~1e-11
constexpr int EB = (E + 255) / 256;        // 6250 edge blocks

typedef unsigned short u16;
typedef __attribute__((ext_vector_type(8))) short bf16x8;  // 8 bf16 = 4 VGPR
typedef __attribute__((ext_vector_type(4))) float f32x4;

// ---------------- bf16 helpers ----------------

__device__ __forceinline__ unsigned bf16rne(float f) {
  unsigned u = __float_as_uint(f);
  return (u + 0x7fffu + ((u >> 16) & 1u)) >> 16;
}
__device__ __forceinline__ unsigned pk(float lo, float hi) {
  return bf16rne(lo) | (bf16rne(hi) << 16);
}
__device__ __forceinline__ void acc8(float (&a)[8], const uint4& u, float wgt) {
  a[0] = fmaf(wgt, __uint_as_float(u.x << 16), a[0]);
  a[1] = fmaf(wgt, __uint_as_float(u.x & 0xffff0000u), a[1]);
  a[2] = fmaf(wgt, __uint_as_float(u.y << 16), a[2]);
  a[3] = fmaf(wgt, __uint_as_float(u.y & 0xffff0000u), a[3]);
  a[4] = fmaf(wgt, __uint_as_float(u.z << 16), a[4]);
  a[5] = fmaf(wgt, __uint_as_float(u.z & 0xffff0000u), a[5]);
  a[6] = fmaf(wgt, __uint_as_float(u.w << 16), a[6]);
  a[7] = fmaf(wgt, __uint_as_float(u.w & 0xffff0000u), a[7]);
}

// ------- fused: degree count (+rank) | x -> bf16 | W -> frag tables --------
// blocks [0,2*EB): even -> edge chunk (b>>1), odd -> convert chunk (b>>1).
// blocks [2*EB, 2*EB+12): weight prep (3072 threads of work).

__global__ __launch_bounds__(256) void k_count_conv(
    const int* __restrict__ dst, int* __restrict__ counts, int* __restrict__ rank,
    const float* __restrict__ x, uint4* __restrict__ xb,
    const float* __restrict__ W1, const float* __restrict__ W2,
    uint4* __restrict__ Wb1, uint4* __restrict__ Wb2) {
  int b = blockIdx.x;
  if (b < 2 * EB) {
    int c = b >> 1;
    if (b & 1) {                             // convert block
      int i = c * 256 + threadIdx.x;         // one uint4 (8 bf16) per thread
      if (i >= N * 16) return;
      const float4* x4 = reinterpret_cast<const float4*>(x);
      float4 v0 = x4[(size_t)i * 2];
      float4 v1 = x4[(size_t)i * 2 + 1];
      uint4 o;
      o.x = pk(v0.x, v0.y);
      o.y = pk(v0.z, v0.w);
      o.z = pk(v1.x, v1.y);
      o.w = pk(v1.z, v1.w);
      xb[i] = o;
    } else {                                 // edge (count) block
      int e = c * 256 + threadIdx.x;
      if (e < E) rank[e] = atomicAdd(&counts[dst[e]], 1);
    }
  } else {                                   // weight prep
    int t = (b - 2 * EB) * 256 + threadIdx.x;
    if (t < 2048) {                          // W1: 8 ct * 4 kc * 64 lanes
      int ct = t >> 8, kc = (t >> 6) & 3, l = t & 63;
      int k0 = kc * 32 + (l >> 4) * 8;
      int c = ct * 16 + (l & 15);
      uint4 o;
      o.x = pk(W1[(k0 + 0) * 128 + c], W1[(k0 + 1) * 128 + c]);
      o.y = pk(W1[(k0 + 2) * 128 + c], W1[(k0 + 3) * 128 + c]);
      o.z = pk(W1[(k0 + 4) * 128 + c], W1[(k0 + 5) * 128 + c]);
      o.w = pk(W1[(k0 + 6) * 128 + c], W1[(k0 + 7) * 128 + c]);
      Wb1[t] = o;
    } else if (t < 3072) {                   // W2: 4 ct * 4 kc * 64 lanes
      int u = t - 2048;
      int ct = u >> 8, kc = (u >> 6) & 3, l = u & 63;
      int k0 = kc * 32 + (l >> 4) * 8;
      int c = ct * 16 + (l & 15);
      uint4 o;
      o.x = pk(W2[(k0 + 0) * 64 + c], W2[(k0 + 1) * 64 + c]);
      o.y = pk(W2[(k0 + 2) * 64 + c], W2[(k0 + 3) * 64 + c]);
      o.z = pk(W2[(k0 + 4) * 64 + c], W2[(k0 + 5) * 64 + c]);
      o.w = pk(W2[(k0 + 6) * 64 + c], W2[(k0 + 7) * 64 + c]);
      Wb2[u] = o;
    }
  }
}

// ---------------- atomic-free slab fill ----------------

__global__ __launch_bounds__(256) void k_fill(
    const int* __restrict__ src, const int* __restrict__ dst,
    const int* __restrict__ rank, int* __restrict__ col) {
  int e = blockIdx.x * 256 + threadIdx.x;
  if (e < E) col[(size_t)dst[e] * CAP + rank[e]] = src[e];
}

// ---------------- MEGA layer 1: agg -> @W1 -> epi -> @W2 -> table ----------
// One block = 16 nodes, 256 threads.
// Phase A: thread (n=tid>>4, d8=tid&15) aggregates 8 dims of node n:
//   acc = sum_{s in in(n)} rsqrt(cnt_s+1)*xb[s] + rsqrt(cnt_n+1)*xb[n]
//   -> bf16 -> lds_a[n][d8*8..]  (row stride 136 u16 = 272B, 2-way banks max)
// Phase B: wave w computes cols [w*32,w*32+32) of acc@W1 (rows = block's 16):
//   v = relu(di[r]*v + b1[c]) * di[r]  -> lds_h (bf16)
// Phase C: wave w computes cols [w*16,w*16+16) of hs@W2 -> xa2 global (bf16).

__global__ __launch_bounds__(256) void k_layer1(
    const uint4* __restrict__ xb, const int* __restrict__ counts,
    const int* __restrict__ col, const float* __restrict__ b1,
    const uint4* __restrict__ Wb1, const uint4* __restrict__ Wb2,
    u16* __restrict__ xa2) {
  __shared__ u16 lds_a[16][136];
  __shared__ u16 lds_h[16][136];
  __shared__ float lds_di[16];
  const int tid = threadIdx.x;
  const int nodeBase = blockIdx.x * 16;

  // ---- phase A: gather-aggregate ----
  {
    const int n = tid >> 4;
    const int d8 = tid & 15;
    const int node = nodeBase + n;
    const int cnt = counts[node];
    const float wself = rsqrtf((float)(cnt + 1));
    if (d8 == 0) lds_di[n] = wself;
    const size_t s0 = (size_t)node * CAP;

    float a[8] = {0, 0, 0, 0, 0, 0, 0, 0};
    acc8(a, xb[(size_t)node * 16 + d8], wself);  // self loop
    int e = 0;
    for (; e + 4 <= cnt; e += 4) {               // full quads, no clamping
      int sA = col[s0 + e];
      int sB = col[s0 + e + 1];
      int sC = col[s0 + e + 2];
      int sD = col[s0 + e + 3];
      float wA = rsqrtf((float)(counts[sA] + 1));
      float wB = rsqrtf((float)(counts[sB] + 1));
      float wC = rsqrtf((float)(counts[sC] + 1));
      float wD = rsqrtf((float)(counts[sD] + 1));
      uint4 vA = xb[(size_t)sA * 16 + d8];
      uint4 vB = xb[(size_t)sB * 16 + d8];
      uint4 vC = xb[(size_t)sC * 16 + d8];
      uint4 vD = xb[(size_t)sD * 16 + d8];
      acc8(a, vA, wA);
      acc8(a, vB, wB);
      acc8(a, vC, wC);
      acc8(a, vD, wD);
    }
    for (; e < cnt; ++e) {                       // exact tail
      int s = col[s0 + e];
      float w = rsqrtf((float)(counts[s] + 1));
      acc8(a, xb[(size_t)s * 16 + d8], w);
    }
    uint4 o;
    o.x = pk(a[0], a[1]);
    o.y = pk(a[2], a[3]);
    o.z = pk(a[4], a[5]);
    o.w = pk(a[6], a[7]);
    *reinterpret_cast<uint4*>(&lds_a[n][d8 * 8]) = o;
  }
  __syncthreads();

  // ---- phase B: acc@W1, epilogue relu(di*v+b1)*di -> lds_h ----
  const int lane = tid & 63;
  const int w = tid >> 6;
  const int lr = lane & 15;
  const int lk = lane >> 4;
  const bf16x8* Wf1 = reinterpret_cast<const bf16x8*>(Wb1);
  const bf16x8* Wf2 = reinterpret_cast<const bf16x8*>(Wb2);
  const f32x4 fz = {0.f, 0.f, 0.f, 0.f};
  {
    bf16x8 af[4];
    #pragma unroll
    for (int kc = 0; kc < 4; ++kc)
      af[kc] = *reinterpret_cast<const bf16x8*>(&lds_a[lr][kc * 32 + lk * 8]);
    f32x4 acc1[2] = {fz, fz};
    #pragma unroll
    for (int kc = 0; kc < 4; ++kc) {
      #pragma unroll
      for (int i = 0; i < 2; ++i) {
        bf16x8 bf = Wf1[((w * 2 + i) * 4 + kc) * 64 + lane];
        acc1[i] = __builtin_amdgcn_mfma_f32_16x16x32_bf16(af[kc], bf, acc1[i], 0, 0, 0);
      }
    }
    #pragma unroll
    for (int i = 0; i < 2; ++i) {
      const int c = (w * 2 + i) * 16 + lr;
      const float bl = b1[c];
      #pragma unroll
      for (int ri = 0; ri < 4; ++ri) {
        const int r = lk * 4 + ri;
        const float di = lds_di[r];
        float v = fmaxf(di * acc1[i][ri] + bl, 0.f) * di;
        lds_h[r][c] = (u16)bf16rne(v);
      }
    }
  }
  __syncthreads();

  // ---- phase C: hs@W2 -> layer-2 table (bf16) ----
  {
    bf16x8 a2[4];
    #pragma unroll
    for (int kc = 0; kc < 4; ++kc)
      a2[kc] = *reinterpret_cast<const bf16x8*>(&lds_h[lr][kc * 32 + lk * 8]);
    f32x4 acc2 = fz;
    #pragma unroll
    for (int kc = 0; kc < 4; ++kc) {
      bf16x8 bf = Wf2[(w * 4 + kc) * 64 + lane];
      acc2 = __builtin_amdgcn_mfma_f32_16x16x32_bf16(a2[kc], bf, acc2, 0, 0, 0);
    }
    #pragma unroll
    for (int ri = 0; ri < 4; ++ri) {
      const int row = nodeBase + lk * 4 + ri;
      xa2[(size_t)row * 64 + w * 16 + lr] = (u16)bf16rne(acc2[ri]);
    }
  }
}

// ---------------- layer-2 aggregation: prescaled bf16 table ----------------
// out[i] = rsqrt(cnt_i+1) * ( sum_s t[s] + t[i] ) + b2    (f32 out)

__global__ __launch_bounds__(256) void k_agg2(
    const uint4* __restrict__ t, const int* __restrict__ counts,
    const int* __restrict__ col, const float* __restrict__ bias,
    float* __restrict__ out) {
  const int node = blockIdx.x * 32 + (threadIdx.x >> 3);
  const int lane = threadIdx.x & 7;            // 8 lanes x 8 dims = 64
  if (node >= N) return;
  const size_t s0 = (size_t)node * CAP;
  const int cnt = counts[node];
  const float di = rsqrtf((float)(cnt + 1));

  float a[8] = {0, 0, 0, 0, 0, 0, 0, 0};
  acc8(a, t[(size_t)node * 8 + lane], 1.0f);   // self loop (prescaled)
  int e = 0;
  for (; e + 4 <= cnt; e += 4) {
    int sA = col[s0 + e];
    int sB = col[s0 + e + 1];
    int sC = col[s0 + e + 2];
    int sD = col[s0 + e + 3];
    uint4 vA = t[(size_t)sA * 8 + lane];
    uint4 vB = t[(size_t)sB * 8 + lane];
    uint4 vC = t[(size_t)sC * 8 + lane];
    uint4 vD = t[(size_t)sD * 8 + lane];
    acc8(a, vA, 1.0f);
    acc8(a, vB, 1.0f);
    acc8(a, vC, 1.0f);
    acc8(a, vD, 1.0f);
  }
  for (; e < cnt; ++e)
    acc8(a, t[(size_t)col[s0 + e] * 8 + lane], 1.0f);

  const float4* b4 = reinterpret_cast<const float4*>(bias) + lane * 2;
  float4 b0 = b4[0], b1v = b4[1];
  float4 r0 = {fmaf(di, a[0], b0.x), fmaf(di, a[1], b0.y),
               fmaf(di, a[2], b0.z), fmaf(di, a[3], b0.w)};
  float4 r1 = {fmaf(di, a[4], b1v.x), fmaf(di, a[5], b1v.y),
               fmaf(di, a[6], b1v.z), fmaf(di, a[7], b1v.w)};
  float4* o4 = reinterpret_cast<float4*>(out) + (size_t)node * 16 + lane * 2;
  o4[0] = r0;
  o4[1] = r1;
}

// ---------------- launch ----------------

extern "C" void kernel_launch(void* const* d_in, const int* in_sizes, int n_in,
                              void* d_out, int out_size, void* d_ws, size_t ws_size,
                              hipStream_t stream) {
  const float* x  = (const float*)d_in[0];
  const int*   ei = (const int*)d_in[1];
  const float* W1 = (const float*)d_in[2];
  const float* b1 = (const float*)d_in[3];
  const float* W2 = (const float*)d_in[4];
  const float* b2 = (const float*)d_in[5];
  float* out = (float*)d_out;
  const int* src = ei;
  const int* dst = ei + E;

  char* p = (char*)d_ws;
  auto alloc = [&](size_t bytes) {
    void* q = p;
    p += (bytes + 255) & ~size_t(255);
    return q;
  };
  int*   counts = (int*)alloc((size_t)N * 4);        // 0.4 MB
  int*   rank   = (int*)alloc((size_t)E * 4);        // 6.4 MB
  int*   col    = (int*)alloc((size_t)N * CAP * 4);  // 22.4 MB slab
  uint4* xb     = (uint4*)alloc((size_t)N * 256);    // 25.6 MB bf16 x (unscaled)
  u16*   xa2    = (u16*)alloc((size_t)N * 64 * 2);   // 12.8 MB layer-2 table
  uint4* Wb1    = (uint4*)alloc(2048 * 16);
  uint4* Wb2    = (uint4*)alloc(1024 * 16);

  (void)hipMemsetAsync(counts, 0, (size_t)N * 4, stream);
  k_count_conv<<<2 * EB + 12, 256, 0, stream>>>(dst, counts, rank, x, xb,
                                                W1, W2, Wb1, Wb2);
  k_fill<<<EB, 256, 0, stream>>>(src, dst, rank, col);

  // layer 1 fused: gather-agg -> @W1 (+bias,relu,*di,*di) -> @W2 -> bf16 table
  k_layer1<<<N / 16, 256, 0, stream>>>(xb, counts, col, b1, Wb1, Wb2, xa2);

  // layer 2: gather-agg over prescaled table, *di + b2 -> f32 out
  k_agg2<<<N / 32, 256, 0, stream>>>(
      reinterpret_cast<const uint4*>(xa2), counts, col, b2, out);
}